// Round 12
// baseline (297.952 us; speedup 1.0000x reference)
//
#include <hip/hip_runtime.h>
#include <hip/hip_cooperative_groups.h>

namespace cg = cooperative_groups;

typedef short short8 __attribute__((ext_vector_type(8)));
typedef float f32x4 __attribute__((ext_vector_type(4)));

#define D 512
#define KDIM 1024

// ---- bf16 helpers (manual, RNE) ----
static __device__ __forceinline__ unsigned short f2b(float f) {
    unsigned u = __builtin_bit_cast(unsigned, f);
    unsigned r = (u + 0x7fffu + ((u >> 16) & 1u)) >> 16;
    return (unsigned short)r;
}
static __device__ __forceinline__ float b2f(unsigned short u) {
    return __builtin_bit_cast(float, ((unsigned)u) << 16);
}
static __device__ __forceinline__ void split(float v, unsigned short& hi, unsigned short& lo) {
    hi = f2b(v);
    lo = f2b(v - b2f(hi));
}

// ---- async global->LDS 16B per lane (linear dest: wave-uniform base + lane*16) ----
static __device__ __forceinline__ void g2lds(const void* g, void* l) {
    __builtin_amdgcn_global_load_lds(
        (const __attribute__((address_space(1))) unsigned int*)g,
        (__attribute__((address_space(3))) unsigned int*)l, 16, 0, 0);
}

// ---- merged pre-pass: leaf reduce (blocks 0..4095) + W split (4096..6143) + pad zero (6144..6239) ----
__global__ void pre_kernel(const float* __restrict__ leaves,
                           const float* __restrict__ wl, const float* __restrict__ wr,
                           unsigned short* __restrict__ Ah7,
                           unsigned short* __restrict__ Wh, unsigned short* __restrict__ Wl,
                           unsigned short* __restrict__ zbase) {
    int b = blockIdx.x;
    if (b < 4096) {
        int t = b * 256 + threadIdx.x;
        int p = t >> 6;
        int kc = (t & 63) << 3;
        const float c13 = 1.0f / 3.0f, c23 = 2.0f / 3.0f;
        const float* child = leaves;
        float4 a0 = *reinterpret_cast<const float4*>(child + (size_t)(4 * p + 0) * D + kc);
        float4 a1 = *reinterpret_cast<const float4*>(child + (size_t)(4 * p + 0) * D + kc + 4);
        float4 b0 = *reinterpret_cast<const float4*>(child + (size_t)(4 * p + 1) * D + kc);
        float4 b1 = *reinterpret_cast<const float4*>(child + (size_t)(4 * p + 1) * D + kc + 4);
        float4 c0 = *reinterpret_cast<const float4*>(child + (size_t)(4 * p + 2) * D + kc);
        float4 c1 = *reinterpret_cast<const float4*>(child + (size_t)(4 * p + 2) * D + kc + 4);
        float4 d0 = *reinterpret_cast<const float4*>(child + (size_t)(4 * p + 3) * D + kc);
        float4 d1 = *reinterpret_cast<const float4*>(child + (size_t)(4 * p + 3) * D + kc + 4);
        float ca[8] = {a0.x, a0.y, a0.z, a0.w, a1.x, a1.y, a1.z, a1.w};
        float cb[8] = {b0.x, b0.y, b0.z, b0.w, b1.x, b1.y, b1.z, b1.w};
        float cc[8] = {c0.x, c0.y, c0.z, c0.w, c1.x, c1.y, c1.z, c1.w};
        float cd[8] = {d0.x, d0.y, d0.z, d0.w, d1.x, d1.y, d1.z, d1.w};
        short8 uh, vh;
#pragma unroll
        for (int j = 0; j < 8; ++j) {
            float u = ca[j] + c23 * cb[j] + c13 * cc[j];
            float v = c13 * cb[j] + c23 * cc[j] + cd[j];
            uh[j] = (short)f2b(u);
            vh[j] = (short)f2b(v);
        }
        *reinterpret_cast<short8*>(&Ah7[(size_t)p * KDIM + kc]) = uh;
        *reinterpret_cast<short8*>(&Ah7[(size_t)p * KDIM + 512 + kc]) = vh;
    } else if (b < 6144) {
        int t = (b - 4096) * 256 + threadIdx.x;
        int e = t >> 10, k = t & 1023;
        float v = (k < 512) ? wl[e * 512 + k] : wr[e * 512 + (k - 512)];
        unsigned short h, l;
        split(v, h, l);
        Wh[t] = h; Wl[t] = l;
    } else {
        int t = (b - 6144) * 256 + threadIdx.x;
        *reinterpret_cast<short8*>(zbase + (size_t)t * 8) = (short8)0;
    }
}

// ---- big-level MFMA GEMM + tanh + fused next-level child-reduce ----
// Products: AhWh always; + AhWl if WLO; + AlWh if ALO. WRL: write next-level Al.
template <int BM, bool ALO, bool WLO, bool WRL>
__global__ __launch_bounds__(256)
void gemm_tanh(const unsigned short* __restrict__ Ah, const unsigned short* __restrict__ Al,
               const unsigned short* __restrict__ Wh, const unsigned short* __restrict__ Wl,
               const float* __restrict__ x,
               unsigned short* __restrict__ nAh, unsigned short* __restrict__ nAl,
               int n) {
    constexpr int MF = (BM == 128) ? 4 : 2;
    constexpr int NF = 4;
    constexpr int APASS = BM / 32;
    __shared__ __align__(16) unsigned short Ahs[BM][64];
    __shared__ __align__(16) unsigned short Als[ALO ? BM : 1][64];
    __shared__ __align__(16) unsigned short Bhs[128][64];
    __shared__ __align__(16) unsigned short Bls[WLO ? 128 : 1][64];
    const int m0 = blockIdx.x * BM;
    const int e0 = blockIdx.y * 128;
    const int tid = threadIdx.x;
    const int lane = tid & 63, wid = tid >> 6;
    const int wr = (wid >> 1) * (BM / 2);
    const int wc = (wid & 1) * 64;

    f32x4 acc[MF][NF];
#pragma unroll
    for (int m = 0; m < MF; ++m)
#pragma unroll
        for (int nn = 0; nn < NF; ++nn) acc[m][nn] = (f32x4){0.f, 0.f, 0.f, 0.f};

    const int lrow = lane >> 3;
    const int lcol = (lane & 7) << 3;

    for (int kb = 0; kb < KDIM; kb += 64) {
#pragma unroll
        for (int p = 0; p < APASS; ++p) {
            int row = p * 32 + wid * 8;
            size_t g = (size_t)(m0 + row + lrow) * KDIM + kb + lcol;
            g2lds(&Ah[g], &Ahs[row][0]);
            if (ALO) g2lds(&Al[g], &Als[ALO ? row : 0][0]);
        }
#pragma unroll
        for (int p = 0; p < 4; ++p) {
            int row = p * 32 + wid * 8;
            size_t g = (size_t)(e0 + row + lrow) * KDIM + kb + lcol;
            g2lds(&Wh[g], &Bhs[row][0]);
            if (WLO) g2lds(&Wl[g], &Bls[WLO ? row : 0][0]);
        }
        __syncthreads();
#pragma unroll
        for (int kk = 0; kk < 64; kk += 32) {
            const int ka = kk + ((lane >> 4) << 3);
            short8 afh[MF], afl[MF], bfh[NF], bfl[NF];
#pragma unroll
            for (int m = 0; m < MF; ++m) {
                afh[m] = *reinterpret_cast<const short8*>(&Ahs[wr + m * 16 + (lane & 15)][ka]);
                if (ALO) afl[m] = *reinterpret_cast<const short8*>(&Als[ALO ? (wr + m * 16 + (lane & 15)) : 0][ka]);
            }
#pragma unroll
            for (int nn = 0; nn < NF; ++nn) {
                bfh[nn] = *reinterpret_cast<const short8*>(&Bhs[wc + nn * 16 + (lane & 15)][ka]);
                if (WLO) bfl[nn] = *reinterpret_cast<const short8*>(&Bls[WLO ? (wc + nn * 16 + (lane & 15)) : 0][ka]);
            }
#pragma unroll
            for (int m = 0; m < MF; ++m)
#pragma unroll
                for (int nn = 0; nn < NF; ++nn) {
                    acc[m][nn] = __builtin_amdgcn_mfma_f32_16x16x32_bf16(afh[m], bfh[nn], acc[m][nn], 0, 0, 0);
                    if (WLO)
                        acc[m][nn] = __builtin_amdgcn_mfma_f32_16x16x32_bf16(afh[m], bfl[nn], acc[m][nn], 0, 0, 0);
                    if (ALO)
                        acc[m][nn] = __builtin_amdgcn_mfma_f32_16x16x32_bf16(afl[m], bfh[nn], acc[m][nn], 0, 0, 0);
                }
        }
        __syncthreads();
    }

    const int dr = (lane >> 4) << 2;
    const int dc = lane & 15;
    const float c13 = 1.0f / 3.0f, c23 = 2.0f / 3.0f;
#pragma unroll
    for (int m = 0; m < MF; ++m) {
        int rbase = m0 + wr + m * 16 + dr;
        if (rbase >= n) continue;
#pragma unroll
        for (int nn = 0; nn < NF; ++nn) {
            int col = e0 + wc + nn * 16 + dc;
            float hv[4];
#pragma unroll
            for (int j = 0; j < 4; ++j) {
                int row = rbase + j;
                hv[j] = (row < n) ? tanhf(acc[m][nn][j] + x[(size_t)row * D + col]) : 0.f;
            }
            int p = rbase >> 2;
            float u = hv[0] + c23 * hv[1] + c13 * hv[2];
            float v = c13 * hv[1] + c23 * hv[2] + hv[3];
            unsigned short h_, l_;
            split(u, h_, l_);
            nAh[(size_t)p * KDIM + col] = h_;
            if (WRL) nAl[(size_t)p * KDIM + col] = l_;
            split(v, h_, l_);
            nAh[(size_t)p * KDIM + 512 + col] = h_;
            if (WRL) nAl[(size_t)p * KDIM + 512 + col] = l_;
        }
    }
}

// ---- tiny-level GEMM tile body: 32x64, 6-deep counted-vmcnt pipeline, bf16x3 ----
// Ends with __syncthreads() so back-to-back calls can't race next-tile staging
// against this tile's last LDS reads.
#define TBUF 6
static __device__ __forceinline__ void tiny_tile(
    const unsigned short* __restrict__ Ah, const unsigned short* __restrict__ Al,
    const unsigned short* __restrict__ Wh, const unsigned short* __restrict__ Wl,
    const float* __restrict__ x,
    unsigned short* __restrict__ nAh, unsigned short* __restrict__ nAl,
    float* __restrict__ out, int n, int m0, int e0, bool finalLevel,
    unsigned short (&AhS)[TBUF][32][64], unsigned short (&AlS)[TBUF][32][64],
    unsigned short (&BhS)[TBUF][64][64], unsigned short (&BlS)[TBUF][64][64]) {
    const int tid = threadIdx.x;
    const int lane = tid & 63, wid = tid >> 6;
    const int lrow = lane >> 3, lcol = (lane & 7) << 3;

    auto stage = [&](int s) {
        int slot = s % TBUF;
        int kb = s * 64;
        {
            int row = wid * 8;
            size_t g = (size_t)(m0 + row + lrow) * KDIM + kb + lcol;
            g2lds(&Ah[g], &AhS[slot][row][0]);
            g2lds(&Al[g], &AlS[slot][row][0]);
        }
#pragma unroll
        for (int p = 0; p < 2; ++p) {
            int row = wid * 16 + p * 8;
            size_t g = (size_t)(e0 + row + lrow) * KDIM + kb + lcol;
            g2lds(&Wh[g], &BhS[slot][row][0]);
            g2lds(&Wl[g], &BlS[slot][row][0]);
        }
    };

    f32x4 acc[2];
    acc[0] = (f32x4){0.f, 0.f, 0.f, 0.f};
    acc[1] = (f32x4){0.f, 0.f, 0.f, 0.f};

    stage(0); stage(1); stage(2); stage(3); stage(4);

#pragma unroll
    for (int t = 0; t < 16; ++t) {
        if (t <= 11)      { asm volatile("s_waitcnt vmcnt(24)" ::: "memory"); }
        else if (t == 12) { asm volatile("s_waitcnt vmcnt(18)" ::: "memory"); }
        else if (t == 13) { asm volatile("s_waitcnt vmcnt(12)" ::: "memory"); }
        else if (t == 14) { asm volatile("s_waitcnt vmcnt(6)"  ::: "memory"); }
        else              { asm volatile("s_waitcnt vmcnt(0)"  ::: "memory"); }
        __builtin_amdgcn_sched_barrier(0);
        __builtin_amdgcn_s_barrier();
        __builtin_amdgcn_sched_barrier(0);
        if (t + 5 < 16) stage(t + 5);
        const int slot = t % TBUF;
#pragma unroll
        for (int kk = 0; kk < 64; kk += 32) {
            const int ka = kk + ((lane >> 4) << 3);
            short8 afh[2], afl[2], bh, bl;
#pragma unroll
            for (int m = 0; m < 2; ++m) {
                afh[m] = *reinterpret_cast<const short8*>(&AhS[slot][m * 16 + (lane & 15)][ka]);
                afl[m] = *reinterpret_cast<const short8*>(&AlS[slot][m * 16 + (lane & 15)][ka]);
            }
            bh = *reinterpret_cast<const short8*>(&BhS[slot][wid * 16 + (lane & 15)][ka]);
            bl = *reinterpret_cast<const short8*>(&BlS[slot][wid * 16 + (lane & 15)][ka]);
#pragma unroll
            for (int m = 0; m < 2; ++m) {
                acc[m] = __builtin_amdgcn_mfma_f32_16x16x32_bf16(afh[m], bh, acc[m], 0, 0, 0);
                acc[m] = __builtin_amdgcn_mfma_f32_16x16x32_bf16(afh[m], bl, acc[m], 0, 0, 0);
                acc[m] = __builtin_amdgcn_mfma_f32_16x16x32_bf16(afl[m], bh, acc[m], 0, 0, 0);
            }
        }
    }

    __syncthreads();   // fence: all LDS reads done before any next-tile staging

    const int dr = (lane >> 4) << 2;
    const int dc = lane & 15;
    const float c13 = 1.0f / 3.0f, c23 = 2.0f / 3.0f;
#pragma unroll
    for (int m = 0; m < 2; ++m) {
        int rbase = m0 + m * 16 + dr;
        if (rbase >= n) continue;
        int col = e0 + wid * 16 + dc;
        float hv[4];
#pragma unroll
        for (int j = 0; j < 4; ++j) {
            int row = rbase + j;
            hv[j] = (row < n) ? tanhf(acc[m][j] + x[(size_t)row * D + col]) : 0.f;
        }
        if (finalLevel) {
            if (rbase == 0) out[col] = hv[0];
        } else {
            int p = rbase >> 2;
            float u = hv[0] + c23 * hv[1] + c13 * hv[2];
            float v = c13 * hv[1] + c23 * hv[2] + hv[3];
            unsigned short h_, l_;
            split(u, h_, l_);
            nAh[(size_t)p * KDIM + col] = h_;
            nAl[(size_t)p * KDIM + col] = l_;
            split(v, h_, l_);
            nAh[(size_t)p * KDIM + 512 + col] = h_;
            nAl[(size_t)p * KDIM + 512 + col] = l_;
        }
    }
}

// ---- standalone tiny kernel (fallback path) ----
template <bool FINAL>
__global__ __launch_bounds__(256)
void gemm_tiny_k(const unsigned short* __restrict__ Ah, const unsigned short* __restrict__ Al,
                 const unsigned short* __restrict__ Wh, const unsigned short* __restrict__ Wl,
                 const float* __restrict__ x,
                 unsigned short* __restrict__ nAh, unsigned short* __restrict__ nAl,
                 float* __restrict__ out, int n) {
    __shared__ __align__(16) unsigned short AhS[TBUF][32][64];
    __shared__ __align__(16) unsigned short AlS[TBUF][32][64];
    __shared__ __align__(16) unsigned short BhS[TBUF][64][64];
    __shared__ __align__(16) unsigned short BlS[TBUF][64][64];
    tiny_tile(Ah, Al, Wh, Wl, x, nAh, nAl, out, n,
              blockIdx.x * 32, blockIdx.y * 64, FINAL, AhS, AlS, BhS, BlS);
}

// ---- cooperative fused tail: levels 5..0, grid = 128 blocks, tile-stride ----
struct TailArgs {
    const unsigned short* Wh;
    const unsigned short* Wl;
    unsigned short* Ah[6];   // levels 0..5
    unsigned short* Al[6];
    const float* vectors;
    float* out;
};

__global__ __launch_bounds__(256)
void coop_tail(TailArgs a) {
    __shared__ __align__(16) unsigned short AhS[TBUF][32][64];
    __shared__ __align__(16) unsigned short AlS[TBUF][32][64];
    __shared__ __align__(16) unsigned short BhS[TBUF][64][64];
    __shared__ __align__(16) unsigned short BlS[TBUF][64][64];
    cg::grid_group grid = cg::this_grid();

    for (int l = 5; l >= 0; --l) {
        int n = 1 << (2 * l);
        int gx = (n + 31) >> 5;
        int tiles = gx * 8;
        for (int t = (int)blockIdx.x; t < tiles; t += (int)gridDim.x) {
            int m0 = (t >> 3) * 32;
            int e0 = (t & 7) * 64;
            int xo = ((1 << (2 * l)) - 1) / 3;   // (4^l-1)/3
            tiny_tile(a.Ah[l], a.Al[l], a.Wh, a.Wl,
                      a.vectors + (size_t)xo * D,
                      (l > 0) ? a.Ah[l - 1] : nullptr,
                      (l > 0) ? a.Al[l - 1] : nullptr,
                      (l == 0) ? a.out : nullptr,
                      n, m0, e0, (l == 0),
                      AhS, AlS, BhS, BlS);
        }
        if (l > 0) grid.sync();
    }
}

extern "C" void kernel_launch(void* const* d_in, const int* in_sizes, int n_in,
                              void* d_out, int out_size, void* d_ws, size_t ws_size,
                              hipStream_t stream) {
    const float* vectors = (const float*)d_in[0];
    const float* wl = (const float*)d_in[1];
    const float* wr = (const float*)d_in[2];
    float* out = (float*)d_out;
    char* ws = (char*)d_ws;

    size_t cur = 0;
    auto alloc = [&](size_t bytes) -> char* {
        char* p = ws + cur;
        cur += (bytes + 255) & ~(size_t)255;
        return p;
    };
    unsigned short* Wh = (unsigned short*)alloc((size_t)512 * 1024 * 2);
    unsigned short* Wl = (unsigned short*)alloc((size_t)512 * 1024 * 2);
    const int arows[8] = {32, 32, 32, 64, 256, 1024, 4096, 16384};
    unsigned short *Ah[8], *Al[8];
    for (int l = 7; l >= 0; --l) {
        Ah[l] = (unsigned short*)alloc((size_t)arows[l] * KDIM * 2);
        Al[l] = (unsigned short*)alloc((size_t)arows[l] * KDIM * 2);  // Al[7], Al[6] unused
    }
    // levels 2,1,0 allocated last & contiguously: 6 x 64KiB = 384 KiB sliver region

    size_t off8 = 0;
    { size_t o = 0, c = 1; for (int l = 0; l <= 8; ++l) { if (l == 8) off8 = o; o += c; c *= 4; } }
    size_t off7 = off8 - 16384;

    // merged pre-pass: leaf reduce + W split + pad zero
    pre_kernel<<<6240, 256, 0, stream>>>(vectors + off8 * (size_t)D, wl, wr,
                                         Ah[7], Wh, Wl, Ah[2]);

    // level 7: n=16384, BM=128, single product Ah*Wh, writes A6 hi only
    gemm_tanh<128, false, false, false><<<dim3(128, 4), 256, 0, stream>>>(
        Ah[7], nullptr, Wh, nullptr, vectors + off7 * (size_t)D, Ah[6], nullptr, 16384);

    // level 6: n=4096, BM=64, A hi-only x split W (AhWh+AhWl), writes A5 hi+lo
    gemm_tanh<64, false, true, true><<<dim3(64, 4), 256, 0, stream>>>(
        Ah[6], nullptr, Wh, Wl, vectors + (off7 - 4096) * (size_t)D, Ah[5], Al[5], 4096);

    // levels 5..0: cooperative kernel at grid 128 (<= half co-residency capacity),
    // with checked launch + fallback to separate pipelined launches.
    TailArgs ta;
    ta.Wh = Wh; ta.Wl = Wl;
    for (int l = 0; l < 6; ++l) { ta.Ah[l] = Ah[l]; ta.Al[l] = Al[l]; }
    ta.vectors = vectors;
    ta.out = out;
    void* kp[] = { &ta };
    hipError_t cerr = hipLaunchCooperativeKernel((void*)coop_tail, dim3(128), dim3(256), kp, 0, stream);
    if (cerr != hipSuccess) {
        const int xo[6] = {0, 1, 5, 21, 85, 341};   // (4^l-1)/3
        for (int l = 5; l >= 1; --l) {
            int n = 1 << (2 * l);
            int gx = (n + 31) / 32;
            gemm_tiny_k<false><<<dim3(gx, 8), 256, 0, stream>>>(
                Ah[l], Al[l], Wh, Wl, vectors + (size_t)xo[l] * D,
                Ah[l - 1], Al[l - 1], nullptr, n);
        }
        gemm_tiny_k<true><<<dim3(1, 8), 256, 0, stream>>>(
            Ah[0], Al[0], Wh, Wl, vectors, nullptr, nullptr, out, 1);
    }
}

// Round 13
// 189.734 us; speedup vs baseline: 1.5704x; 1.5704x over previous
//
#include <hip/hip_runtime.h>

typedef short short8 __attribute__((ext_vector_type(8)));
typedef float f32x4 __attribute__((ext_vector_type(4)));

#define D 512
#define KDIM 1024

// ---- bf16 helpers (manual, RNE) ----
static __device__ __forceinline__ unsigned short f2b(float f) {
    unsigned u = __builtin_bit_cast(unsigned, f);
    unsigned r = (u + 0x7fffu + ((u >> 16) & 1u)) >> 16;
    return (unsigned short)r;
}
static __device__ __forceinline__ float b2f(unsigned short u) {
    return __builtin_bit_cast(float, ((unsigned)u) << 16);
}
static __device__ __forceinline__ void split(float v, unsigned short& hi, unsigned short& lo) {
    hi = f2b(v);
    lo = f2b(v - b2f(hi));
}

// ---- async global->LDS 16B per lane (linear dest: wave-uniform base + lane*16) ----
static __device__ __forceinline__ void g2lds(const void* g, void* l) {
    __builtin_amdgcn_global_load_lds(
        (const __attribute__((address_space(1))) unsigned int*)g,
        (__attribute__((address_space(3))) unsigned int*)l, 16, 0, 0);
}

// ---- merged pre-pass: leaf reduce (blocks 0..4095) + W split (4096..6143) + pad zero (6144..6239) ----
__global__ void pre_kernel(const float* __restrict__ leaves,
                           const float* __restrict__ wl, const float* __restrict__ wr,
                           unsigned short* __restrict__ Ah7,
                           unsigned short* __restrict__ Wh, unsigned short* __restrict__ Wl,
                           unsigned short* __restrict__ zbase) {
    int b = blockIdx.x;
    if (b < 4096) {
        int t = b * 256 + threadIdx.x;
        int p = t >> 6;
        int kc = (t & 63) << 3;
        const float c13 = 1.0f / 3.0f, c23 = 2.0f / 3.0f;
        const float* child = leaves;
        float4 a0 = *reinterpret_cast<const float4*>(child + (size_t)(4 * p + 0) * D + kc);
        float4 a1 = *reinterpret_cast<const float4*>(child + (size_t)(4 * p + 0) * D + kc + 4);
        float4 b0 = *reinterpret_cast<const float4*>(child + (size_t)(4 * p + 1) * D + kc);
        float4 b1 = *reinterpret_cast<const float4*>(child + (size_t)(4 * p + 1) * D + kc + 4);
        float4 c0 = *reinterpret_cast<const float4*>(child + (size_t)(4 * p + 2) * D + kc);
        float4 c1 = *reinterpret_cast<const float4*>(child + (size_t)(4 * p + 2) * D + kc + 4);
        float4 d0 = *reinterpret_cast<const float4*>(child + (size_t)(4 * p + 3) * D + kc);
        float4 d1 = *reinterpret_cast<const float4*>(child + (size_t)(4 * p + 3) * D + kc + 4);
        float ca[8] = {a0.x, a0.y, a0.z, a0.w, a1.x, a1.y, a1.z, a1.w};
        float cb[8] = {b0.x, b0.y, b0.z, b0.w, b1.x, b1.y, b1.z, b1.w};
        float cc[8] = {c0.x, c0.y, c0.z, c0.w, c1.x, c1.y, c1.z, c1.w};
        float cd[8] = {d0.x, d0.y, d0.z, d0.w, d1.x, d1.y, d1.z, d1.w};
        short8 uh, vh;
#pragma unroll
        for (int j = 0; j < 8; ++j) {
            float u = ca[j] + c23 * cb[j] + c13 * cc[j];
            float v = c13 * cb[j] + c23 * cc[j] + cd[j];
            uh[j] = (short)f2b(u);
            vh[j] = (short)f2b(v);
        }
        *reinterpret_cast<short8*>(&Ah7[(size_t)p * KDIM + kc]) = uh;
        *reinterpret_cast<short8*>(&Ah7[(size_t)p * KDIM + 512 + kc]) = vh;
    } else if (b < 6144) {
        int t = (b - 4096) * 256 + threadIdx.x;
        int e = t >> 10, k = t & 1023;
        float v = (k < 512) ? wl[e * 512 + k] : wr[e * 512 + (k - 512)];
        unsigned short h, l;
        split(v, h, l);
        Wh[t] = h; Wl[t] = l;
    } else {
        int t = (b - 6144) * 256 + threadIdx.x;
        *reinterpret_cast<short8*>(zbase + (size_t)t * 8) = (short8)0;
    }
}

// ---- big-level MFMA GEMM + tanh + fused next-level child-reduce ----
// Products: AhWh always; + AhWl if WLO; + AlWh if ALO. WRL: write next-level Al.
// L7: <128,false,false,false> = AhWh only -> A6 hi only.
// L6: <64,false,false,true>   = AhWh only -> A5 hi+lo.
template <int BM, bool ALO, bool WLO, bool WRL>
__global__ __launch_bounds__(256)
void gemm_tanh(const unsigned short* __restrict__ Ah, const unsigned short* __restrict__ Al,
               const unsigned short* __restrict__ Wh, const unsigned short* __restrict__ Wl,
               const float* __restrict__ x,
               unsigned short* __restrict__ nAh, unsigned short* __restrict__ nAl,
               int n) {
    constexpr int MF = (BM == 128) ? 4 : 2;
    constexpr int NF = 4;
    constexpr int APASS = BM / 32;
    __shared__ __align__(16) unsigned short Ahs[BM][64];
    __shared__ __align__(16) unsigned short Als[ALO ? BM : 1][64];
    __shared__ __align__(16) unsigned short Bhs[128][64];
    __shared__ __align__(16) unsigned short Bls[WLO ? 128 : 1][64];
    const int m0 = blockIdx.x * BM;
    const int e0 = blockIdx.y * 128;
    const int tid = threadIdx.x;
    const int lane = tid & 63, wid = tid >> 6;
    const int wr = (wid >> 1) * (BM / 2);
    const int wc = (wid & 1) * 64;

    f32x4 acc[MF][NF];
#pragma unroll
    for (int m = 0; m < MF; ++m)
#pragma unroll
        for (int nn = 0; nn < NF; ++nn) acc[m][nn] = (f32x4){0.f, 0.f, 0.f, 0.f};

    const int lrow = lane >> 3;
    const int lcol = (lane & 7) << 3;

    for (int kb = 0; kb < KDIM; kb += 64) {
#pragma unroll
        for (int p = 0; p < APASS; ++p) {
            int row = p * 32 + wid * 8;
            size_t g = (size_t)(m0 + row + lrow) * KDIM + kb + lcol;
            g2lds(&Ah[g], &Ahs[row][0]);
            if (ALO) g2lds(&Al[g], &Als[ALO ? row : 0][0]);
        }
#pragma unroll
        for (int p = 0; p < 4; ++p) {
            int row = p * 32 + wid * 8;
            size_t g = (size_t)(e0 + row + lrow) * KDIM + kb + lcol;
            g2lds(&Wh[g], &Bhs[row][0]);
            if (WLO) g2lds(&Wl[g], &Bls[WLO ? row : 0][0]);
        }
        __syncthreads();
#pragma unroll
        for (int kk = 0; kk < 64; kk += 32) {
            const int ka = kk + ((lane >> 4) << 3);
            short8 afh[MF], afl[MF], bfh[NF], bfl[NF];
#pragma unroll
            for (int m = 0; m < MF; ++m) {
                afh[m] = *reinterpret_cast<const short8*>(&Ahs[wr + m * 16 + (lane & 15)][ka]);
                if (ALO) afl[m] = *reinterpret_cast<const short8*>(&Als[ALO ? (wr + m * 16 + (lane & 15)) : 0][ka]);
            }
#pragma unroll
            for (int nn = 0; nn < NF; ++nn) {
                bfh[nn] = *reinterpret_cast<const short8*>(&Bhs[wc + nn * 16 + (lane & 15)][ka]);
                if (WLO) bfl[nn] = *reinterpret_cast<const short8*>(&Bls[WLO ? (wc + nn * 16 + (lane & 15)) : 0][ka]);
            }
#pragma unroll
            for (int m = 0; m < MF; ++m)
#pragma unroll
                for (int nn = 0; nn < NF; ++nn) {
                    acc[m][nn] = __builtin_amdgcn_mfma_f32_16x16x32_bf16(afh[m], bfh[nn], acc[m][nn], 0, 0, 0);
                    if (WLO)
                        acc[m][nn] = __builtin_amdgcn_mfma_f32_16x16x32_bf16(afh[m], bfl[nn], acc[m][nn], 0, 0, 0);
                    if (ALO)
                        acc[m][nn] = __builtin_amdgcn_mfma_f32_16x16x32_bf16(afl[m], bfh[nn], acc[m][nn], 0, 0, 0);
                }
        }
        __syncthreads();
    }

    const int dr = (lane >> 4) << 2;
    const int dc = lane & 15;
    const float c13 = 1.0f / 3.0f, c23 = 2.0f / 3.0f;
#pragma unroll
    for (int m = 0; m < MF; ++m) {
        int rbase = m0 + wr + m * 16 + dr;
        if (rbase >= n) continue;
#pragma unroll
        for (int nn = 0; nn < NF; ++nn) {
            int col = e0 + wc + nn * 16 + dc;
            float hv[4];
#pragma unroll
            for (int j = 0; j < 4; ++j) {
                int row = rbase + j;
                hv[j] = (row < n) ? tanhf(acc[m][nn][j] + x[(size_t)row * D + col]) : 0.f;
            }
            int p = rbase >> 2;
            float u = hv[0] + c23 * hv[1] + c13 * hv[2];
            float v = c13 * hv[1] + c23 * hv[2] + hv[3];
            unsigned short h_, l_;
            split(u, h_, l_);
            nAh[(size_t)p * KDIM + col] = h_;
            if (WRL) nAl[(size_t)p * KDIM + col] = l_;
            split(v, h_, l_);
            nAh[(size_t)p * KDIM + 512 + col] = h_;
            if (WRL) nAl[(size_t)p * KDIM + 512 + col] = l_;
        }
    }
}

// ---- tiny-level GEMM: 32x64 tile, 6-deep counted-vmcnt pipeline, full bf16x3 ----
#define TBUF 6
template <bool FINAL>
__global__ __launch_bounds__(256)
void gemm_tiny(const unsigned short* __restrict__ Ah, const unsigned short* __restrict__ Al,
               const unsigned short* __restrict__ Wh, const unsigned short* __restrict__ Wl,
               const float* __restrict__ x,
               unsigned short* __restrict__ nAh, unsigned short* __restrict__ nAl,
               float* __restrict__ out, int n) {
    __shared__ __align__(16) unsigned short AhS[TBUF][32][64];
    __shared__ __align__(16) unsigned short AlS[TBUF][32][64];
    __shared__ __align__(16) unsigned short BhS[TBUF][64][64];
    __shared__ __align__(16) unsigned short BlS[TBUF][64][64];
    const int m0 = blockIdx.x * 32;
    const int e0 = blockIdx.y * 64;
    const int tid = threadIdx.x;
    const int lane = tid & 63, wid = tid >> 6;
    const int lrow = lane >> 3, lcol = (lane & 7) << 3;

    auto stage = [&](int s) {
        int slot = s % TBUF;
        int kb = s * 64;
        {
            int row = wid * 8;
            size_t g = (size_t)(m0 + row + lrow) * KDIM + kb + lcol;
            g2lds(&Ah[g], &AhS[slot][row][0]);
            g2lds(&Al[g], &AlS[slot][row][0]);
        }
#pragma unroll
        for (int p = 0; p < 2; ++p) {
            int row = wid * 16 + p * 8;
            size_t g = (size_t)(e0 + row + lrow) * KDIM + kb + lcol;
            g2lds(&Wh[g], &BhS[slot][row][0]);
            g2lds(&Wl[g], &BlS[slot][row][0]);
        }
    };

    f32x4 acc[2];
    acc[0] = (f32x4){0.f, 0.f, 0.f, 0.f};
    acc[1] = (f32x4){0.f, 0.f, 0.f, 0.f};

    stage(0); stage(1); stage(2); stage(3); stage(4);

#pragma unroll
    for (int t = 0; t < 16; ++t) {
        if (t <= 11)      { asm volatile("s_waitcnt vmcnt(24)" ::: "memory"); }
        else if (t == 12) { asm volatile("s_waitcnt vmcnt(18)" ::: "memory"); }
        else if (t == 13) { asm volatile("s_waitcnt vmcnt(12)" ::: "memory"); }
        else if (t == 14) { asm volatile("s_waitcnt vmcnt(6)"  ::: "memory"); }
        else              { asm volatile("s_waitcnt vmcnt(0)"  ::: "memory"); }
        __builtin_amdgcn_sched_barrier(0);
        __builtin_amdgcn_s_barrier();
        __builtin_amdgcn_sched_barrier(0);
        if (t + 5 < 16) stage(t + 5);
        const int slot = t % TBUF;
#pragma unroll
        for (int kk = 0; kk < 64; kk += 32) {
            const int ka = kk + ((lane >> 4) << 3);
            short8 afh[2], afl[2], bh, bl;
#pragma unroll
            for (int m = 0; m < 2; ++m) {
                afh[m] = *reinterpret_cast<const short8*>(&AhS[slot][m * 16 + (lane & 15)][ka]);
                afl[m] = *reinterpret_cast<const short8*>(&AlS[slot][m * 16 + (lane & 15)][ka]);
            }
            bh = *reinterpret_cast<const short8*>(&BhS[slot][wid * 16 + (lane & 15)][ka]);
            bl = *reinterpret_cast<const short8*>(&BlS[slot][wid * 16 + (lane & 15)][ka]);
#pragma unroll
            for (int m = 0; m < 2; ++m) {
                acc[m] = __builtin_amdgcn_mfma_f32_16x16x32_bf16(afh[m], bh, acc[m], 0, 0, 0);
                acc[m] = __builtin_amdgcn_mfma_f32_16x16x32_bf16(afh[m], bl, acc[m], 0, 0, 0);
                acc[m] = __builtin_amdgcn_mfma_f32_16x16x32_bf16(afl[m], bh, acc[m], 0, 0, 0);
            }
        }
    }

    const int dr = (lane >> 4) << 2;
    const int dc = lane & 15;
    const float c13 = 1.0f / 3.0f, c23 = 2.0f / 3.0f;
#pragma unroll
    for (int m = 0; m < 2; ++m) {
        int rbase = m0 + m * 16 + dr;
        if (rbase >= n) continue;
        int col = e0 + wid * 16 + dc;
        float hv[4];
#pragma unroll
        for (int j = 0; j < 4; ++j) {
            int row = rbase + j;
            hv[j] = (row < n) ? tanhf(acc[m][j] + x[(size_t)row * D + col]) : 0.f;
        }
        if (FINAL) {
            if (rbase == 0) out[col] = hv[0];
        } else {
            int p = rbase >> 2;
            float u = hv[0] + c23 * hv[1] + c13 * hv[2];
            float v = c13 * hv[1] + c23 * hv[2] + hv[3];
            unsigned short h_, l_;
            split(u, h_, l_);
            nAh[(size_t)p * KDIM + col] = h_;
            nAl[(size_t)p * KDIM + col] = l_;
            split(v, h_, l_);
            nAh[(size_t)p * KDIM + 512 + col] = h_;
            nAl[(size_t)p * KDIM + 512 + col] = l_;
        }
    }
}

extern "C" void kernel_launch(void* const* d_in, const int* in_sizes, int n_in,
                              void* d_out, int out_size, void* d_ws, size_t ws_size,
                              hipStream_t stream) {
    const float* vectors = (const float*)d_in[0];
    const float* wl = (const float*)d_in[1];
    const float* wr = (const float*)d_in[2];
    float* out = (float*)d_out;
    char* ws = (char*)d_ws;

    size_t cur = 0;
    auto alloc = [&](size_t bytes) -> char* {
        char* p = ws + cur;
        cur += (bytes + 255) & ~(size_t)255;
        return p;
    };
    unsigned short* Wh = (unsigned short*)alloc((size_t)512 * 1024 * 2);
    unsigned short* Wl = (unsigned short*)alloc((size_t)512 * 1024 * 2);
    const int arows[8] = {32, 32, 32, 64, 256, 1024, 4096, 16384};
    unsigned short *Ah[8], *Al[8];
    for (int l = 7; l >= 0; --l) {
        Ah[l] = (unsigned short*)alloc((size_t)arows[l] * KDIM * 2);
        Al[l] = (unsigned short*)alloc((size_t)arows[l] * KDIM * 2);  // Al[7], Al[6] unused
    }
    // levels 2,1,0 allocated last & contiguously: 6 x 64KiB = 384 KiB sliver region

    size_t off8 = 0;
    { size_t o = 0, c = 1; for (int l = 0; l <= 8; ++l) { if (l == 8) off8 = o; o += c; c *= 4; } }
    size_t off7 = off8 - 16384;

    // merged pre-pass: leaf reduce + W split + pad zero
    pre_kernel<<<6240, 256, 0, stream>>>(vectors + off8 * (size_t)D, wl, wr,
                                         Ah[7], Wh, Wl, Ah[2]);

    // level 7: n=16384, BM=128, single product Ah*Wh, writes A6 hi only
    gemm_tanh<128, false, false, false><<<dim3(128, 4), 256, 0, stream>>>(
        Ah[7], nullptr, Wh, nullptr, vectors + off7 * (size_t)D, Ah[6], nullptr, 16384);

    // level 6: n=4096, BM=64, single product Ah*Wh, writes A5 hi+lo
    gemm_tanh<64, false, false, true><<<dim3(64, 4), 256, 0, stream>>>(
        Ah[6], nullptr, Wh, nullptr, vectors + (off7 - 4096) * (size_t)D, Ah[5], Al[5], 4096);

    // levels 5..0: separate tiny pipelined launches (full bf16x3)
    const int xo[6] = {0, 1, 5, 21, 85, 341};   // (4^l-1)/3
    for (int l = 5; l >= 1; --l) {
        int n = 1 << (2 * l);
        int gx = (n + 31) / 32;
        gemm_tiny<false><<<dim3(gx, 8), 256, 0, stream>>>(
            Ah[l], Al[l], Wh, Wl, vectors + (size_t)xo[l] * D,
            Ah[l - 1], Al[l - 1], nullptr, n);
    }
    gemm_tiny<true><<<dim3(1, 8), 256, 0, stream>>>(
        Ah[0], Al[0], Wh, Wl, vectors, nullptr, nullptr, out, 1);
}

// Round 14
// 189.625 us; speedup vs baseline: 1.5713x; 1.0006x over previous
//
#include <hip/hip_runtime.h>

typedef short short8 __attribute__((ext_vector_type(8)));
typedef float f32x4 __attribute__((ext_vector_type(4)));

#define D 512
#define KDIM 1024

// ---- bf16 helpers (manual, RNE) ----
static __device__ __forceinline__ unsigned short f2b(float f) {
    unsigned u = __builtin_bit_cast(unsigned, f);
    unsigned r = (u + 0x7fffu + ((u >> 16) & 1u)) >> 16;
    return (unsigned short)r;
}
static __device__ __forceinline__ float b2f(unsigned short u) {
    return __builtin_bit_cast(float, ((unsigned)u) << 16);
}
static __device__ __forceinline__ void split(float v, unsigned short& hi, unsigned short& lo) {
    hi = f2b(v);
    lo = f2b(v - b2f(hi));
}

// ---- async global->LDS 16B per lane (linear dest: wave-uniform base + lane*16) ----
static __device__ __forceinline__ void g2lds(const void* g, void* l) {
    __builtin_amdgcn_global_load_lds(
        (const __attribute__((address_space(1))) unsigned int*)g,
        (__attribute__((address_space(3))) unsigned int*)l, 16, 0, 0);
}

// ---- merged pre-pass: leaf reduce (blocks 0..4095) + W split (4096..6143) + pad zero (6144..6239) ----
__global__ void pre_kernel(const float* __restrict__ leaves,
                           const float* __restrict__ wl, const float* __restrict__ wr,
                           unsigned short* __restrict__ Ah7,
                           unsigned short* __restrict__ Wh, unsigned short* __restrict__ Wl,
                           unsigned short* __restrict__ zbase) {
    int b = blockIdx.x;
    if (b < 4096) {
        int t = b * 256 + threadIdx.x;
        int p = t >> 6;
        int kc = (t & 63) << 3;
        const float c13 = 1.0f / 3.0f, c23 = 2.0f / 3.0f;
        const float* child = leaves;
        float4 a0 = *reinterpret_cast<const float4*>(child + (size_t)(4 * p + 0) * D + kc);
        float4 a1 = *reinterpret_cast<const float4*>(child + (size_t)(4 * p + 0) * D + kc + 4);
        float4 b0 = *reinterpret_cast<const float4*>(child + (size_t)(4 * p + 1) * D + kc);
        float4 b1 = *reinterpret_cast<const float4*>(child + (size_t)(4 * p + 1) * D + kc + 4);
        float4 c0 = *reinterpret_cast<const float4*>(child + (size_t)(4 * p + 2) * D + kc);
        float4 c1 = *reinterpret_cast<const float4*>(child + (size_t)(4 * p + 2) * D + kc + 4);
        float4 d0 = *reinterpret_cast<const float4*>(child + (size_t)(4 * p + 3) * D + kc);
        float4 d1 = *reinterpret_cast<const float4*>(child + (size_t)(4 * p + 3) * D + kc + 4);
        float ca[8] = {a0.x, a0.y, a0.z, a0.w, a1.x, a1.y, a1.z, a1.w};
        float cb[8] = {b0.x, b0.y, b0.z, b0.w, b1.x, b1.y, b1.z, b1.w};
        float cc[8] = {c0.x, c0.y, c0.z, c0.w, c1.x, c1.y, c1.z, c1.w};
        float cd[8] = {d0.x, d0.y, d0.z, d0.w, d1.x, d1.y, d1.z, d1.w};
        short8 uh, vh;
#pragma unroll
        for (int j = 0; j < 8; ++j) {
            float u = ca[j] + c23 * cb[j] + c13 * cc[j];
            float v = c13 * cb[j] + c23 * cc[j] + cd[j];
            uh[j] = (short)f2b(u);
            vh[j] = (short)f2b(v);
        }
        *reinterpret_cast<short8*>(&Ah7[(size_t)p * KDIM + kc]) = uh;
        *reinterpret_cast<short8*>(&Ah7[(size_t)p * KDIM + 512 + kc]) = vh;
    } else if (b < 6144) {
        int t = (b - 4096) * 256 + threadIdx.x;
        int e = t >> 10, k = t & 1023;
        float v = (k < 512) ? wl[e * 512 + k] : wr[e * 512 + (k - 512)];
        unsigned short h, l;
        split(v, h, l);
        Wh[t] = h; Wl[t] = l;
    } else {
        int t = (b - 6144) * 256 + threadIdx.x;
        *reinterpret_cast<short8*>(zbase + (size_t)t * 8) = (short8)0;
    }
}

// ---- L7 GEMM: BM=128, single product Ah*Wh, 2-phase loop (HBM-BW-bound) ----
__global__ __launch_bounds__(256)
void gemm_l7(const unsigned short* __restrict__ Ah, const unsigned short* __restrict__ Wh,
             const float* __restrict__ x, unsigned short* __restrict__ nAh, int n) {
    __shared__ __align__(16) unsigned short Ahs[128][64];
    __shared__ __align__(16) unsigned short Bhs[128][64];
    const int m0 = blockIdx.x * 128;
    const int e0 = blockIdx.y * 128;
    const int tid = threadIdx.x;
    const int lane = tid & 63, wid = tid >> 6;
    const int wr = (wid >> 1) * 64;
    const int wc = (wid & 1) * 64;

    f32x4 acc[4][4];
#pragma unroll
    for (int m = 0; m < 4; ++m)
#pragma unroll
        for (int nn = 0; nn < 4; ++nn) acc[m][nn] = (f32x4){0.f, 0.f, 0.f, 0.f};

    const int lrow = lane >> 3;
    const int lcol = (lane & 7) << 3;

    for (int kb = 0; kb < KDIM; kb += 64) {
#pragma unroll
        for (int p = 0; p < 4; ++p) {
            int row = p * 32 + wid * 8;
            g2lds(&Ah[(size_t)(m0 + row + lrow) * KDIM + kb + lcol], &Ahs[row][0]);
            g2lds(&Wh[(size_t)(e0 + row + lrow) * KDIM + kb + lcol], &Bhs[row][0]);
        }
        __syncthreads();
#pragma unroll
        for (int kk = 0; kk < 64; kk += 32) {
            const int ka = kk + ((lane >> 4) << 3);
            short8 af[4], bf[4];
#pragma unroll
            for (int m = 0; m < 4; ++m)
                af[m] = *reinterpret_cast<const short8*>(&Ahs[wr + m * 16 + (lane & 15)][ka]);
#pragma unroll
            for (int nn = 0; nn < 4; ++nn)
                bf[nn] = *reinterpret_cast<const short8*>(&Bhs[wc + nn * 16 + (lane & 15)][ka]);
#pragma unroll
            for (int m = 0; m < 4; ++m)
#pragma unroll
                for (int nn = 0; nn < 4; ++nn)
                    acc[m][nn] = __builtin_amdgcn_mfma_f32_16x16x32_bf16(af[m], bf[nn], acc[m][nn], 0, 0, 0);
        }
        __syncthreads();
    }

    const int dr = (lane >> 4) << 2;
    const int dc = lane & 15;
    const float c13 = 1.0f / 3.0f, c23 = 2.0f / 3.0f;
#pragma unroll
    for (int m = 0; m < 4; ++m) {
        int rbase = m0 + wr + m * 16 + dr;
        if (rbase >= n) continue;
#pragma unroll
        for (int nn = 0; nn < 4; ++nn) {
            int col = e0 + wc + nn * 16 + dc;
            float hv[4];
#pragma unroll
            for (int j = 0; j < 4; ++j) {
                int row = rbase + j;
                hv[j] = (row < n) ? tanhf(acc[m][nn][j] + x[(size_t)row * D + col]) : 0.f;
            }
            int p = rbase >> 2;
            float u = hv[0] + c23 * hv[1] + c13 * hv[2];
            float v = c13 * hv[1] + c23 * hv[2] + hv[3];
            nAh[(size_t)p * KDIM + col] = f2b(u);
            nAh[(size_t)p * KDIM + 512 + col] = f2b(v);
        }
    }
}

// ---- L6 GEMM: BM=64 x BN=128, single product, 4-deep counted-vmcnt pipeline ----
// Writes A5 hi+lo. Same hazard distance (stage(t+3) -> slot (t-1)%4) as the
// proven TBUF=6 tiny kernel. 6 loads/wave/stage -> steady vmcnt(12).
#define MBUF 4
__global__ __launch_bounds__(256)
void gemm_mid(const unsigned short* __restrict__ Ah, const unsigned short* __restrict__ Wh,
              const float* __restrict__ x,
              unsigned short* __restrict__ nAh, unsigned short* __restrict__ nAl, int n) {
    __shared__ __align__(16) unsigned short AhS[MBUF][64][64];
    __shared__ __align__(16) unsigned short BhS[MBUF][128][64];
    const int m0 = blockIdx.x * 64;
    const int e0 = blockIdx.y * 128;
    const int tid = threadIdx.x;
    const int lane = tid & 63, wid = tid >> 6;
    const int wm = (wid >> 1) * 32;
    const int wc = (wid & 1) * 64;
    const int lrow = lane >> 3, lcol = (lane & 7) << 3;

    auto stage = [&](int s) {
        int slot = s & 3;
        int kb = s * 64;
#pragma unroll
        for (int p = 0; p < 2; ++p) {
            int row = wid * 16 + p * 8;
            g2lds(&Ah[(size_t)(m0 + row + lrow) * KDIM + kb + lcol], &AhS[slot][row][0]);
        }
#pragma unroll
        for (int p = 0; p < 4; ++p) {
            int row = wid * 32 + p * 8;
            g2lds(&Wh[(size_t)(e0 + row + lrow) * KDIM + kb + lcol], &BhS[slot][row][0]);
        }
    };

    f32x4 acc[2][4];
#pragma unroll
    for (int m = 0; m < 2; ++m)
#pragma unroll
        for (int nn = 0; nn < 4; ++nn) acc[m][nn] = (f32x4){0.f, 0.f, 0.f, 0.f};

    stage(0); stage(1); stage(2);

#pragma unroll
    for (int t = 0; t < 16; ++t) {
        if (t <= 13)      { asm volatile("s_waitcnt vmcnt(12)" ::: "memory"); }
        else if (t == 14) { asm volatile("s_waitcnt vmcnt(6)"  ::: "memory"); }
        else              { asm volatile("s_waitcnt vmcnt(0)"  ::: "memory"); }
        __builtin_amdgcn_sched_barrier(0);
        __builtin_amdgcn_s_barrier();
        __builtin_amdgcn_sched_barrier(0);
        if (t + 3 < 16) stage(t + 3);
        const int slot = t & 3;
#pragma unroll
        for (int kk = 0; kk < 64; kk += 32) {
            const int ka = kk + ((lane >> 4) << 3);
            short8 af[2], bf[4];
#pragma unroll
            for (int m = 0; m < 2; ++m)
                af[m] = *reinterpret_cast<const short8*>(&AhS[slot][wm + m * 16 + (lane & 15)][ka]);
#pragma unroll
            for (int nn = 0; nn < 4; ++nn)
                bf[nn] = *reinterpret_cast<const short8*>(&BhS[slot][wc + nn * 16 + (lane & 15)][ka]);
#pragma unroll
            for (int m = 0; m < 2; ++m)
#pragma unroll
                for (int nn = 0; nn < 4; ++nn)
                    acc[m][nn] = __builtin_amdgcn_mfma_f32_16x16x32_bf16(af[m], bf[nn], acc[m][nn], 0, 0, 0);
        }
    }

    const int dr = (lane >> 4) << 2;
    const int dc = lane & 15;
    const float c13 = 1.0f / 3.0f, c23 = 2.0f / 3.0f;
#pragma unroll
    for (int m = 0; m < 2; ++m) {
        int rbase = m0 + wm + m * 16 + dr;
        if (rbase >= n) continue;
#pragma unroll
        for (int nn = 0; nn < 4; ++nn) {
            int col = e0 + wc + nn * 16 + dc;
            float hv[4];
#pragma unroll
            for (int j = 0; j < 4; ++j) {
                int row = rbase + j;
                hv[j] = (row < n) ? tanhf(acc[m][nn][j] + x[(size_t)row * D + col]) : 0.f;
            }
            int p = rbase >> 2;
            float u = hv[0] + c23 * hv[1] + c13 * hv[2];
            float v = c13 * hv[1] + c23 * hv[2] + hv[3];
            unsigned short h_, l_;
            split(u, h_, l_);
            nAh[(size_t)p * KDIM + col] = h_;
            nAl[(size_t)p * KDIM + col] = l_;
            split(v, h_, l_);
            nAh[(size_t)p * KDIM + 512 + col] = h_;
            nAl[(size_t)p * KDIM + 512 + col] = l_;
        }
    }
}

// ---- tiny-level GEMM: 32x64 tile, 6-deep counted-vmcnt pipeline, full bf16x3 ----
#define TBUF 6
template <bool FINAL>
__global__ __launch_bounds__(256)
void gemm_tiny(const unsigned short* __restrict__ Ah, const unsigned short* __restrict__ Al,
               const unsigned short* __restrict__ Wh, const unsigned short* __restrict__ Wl,
               const float* __restrict__ x,
               unsigned short* __restrict__ nAh, unsigned short* __restrict__ nAl,
               float* __restrict__ out, int n) {
    __shared__ __align__(16) unsigned short AhS[TBUF][32][64];
    __shared__ __align__(16) unsigned short AlS[TBUF][32][64];
    __shared__ __align__(16) unsigned short BhS[TBUF][64][64];
    __shared__ __align__(16) unsigned short BlS[TBUF][64][64];
    const int m0 = blockIdx.x * 32;
    const int e0 = blockIdx.y * 64;
    const int tid = threadIdx.x;
    const int lane = tid & 63, wid = tid >> 6;
    const int lrow = lane >> 3, lcol = (lane & 7) << 3;

    auto stage = [&](int s) {
        int slot = s % TBUF;
        int kb = s * 64;
        {
            int row = wid * 8;
            size_t g = (size_t)(m0 + row + lrow) * KDIM + kb + lcol;
            g2lds(&Ah[g], &AhS[slot][row][0]);
            g2lds(&Al[g], &AlS[slot][row][0]);
        }
#pragma unroll
        for (int p = 0; p < 2; ++p) {
            int row = wid * 16 + p * 8;
            size_t g = (size_t)(e0 + row + lrow) * KDIM + kb + lcol;
            g2lds(&Wh[g], &BhS[slot][row][0]);
            g2lds(&Wl[g], &BlS[slot][row][0]);
        }
    };

    f32x4 acc[2];
    acc[0] = (f32x4){0.f, 0.f, 0.f, 0.f};
    acc[1] = (f32x4){0.f, 0.f, 0.f, 0.f};

    stage(0); stage(1); stage(2); stage(3); stage(4);

#pragma unroll
    for (int t = 0; t < 16; ++t) {
        if (t <= 11)      { asm volatile("s_waitcnt vmcnt(24)" ::: "memory"); }
        else if (t == 12) { asm volatile("s_waitcnt vmcnt(18)" ::: "memory"); }
        else if (t == 13) { asm volatile("s_waitcnt vmcnt(12)" ::: "memory"); }
        else if (t == 14) { asm volatile("s_waitcnt vmcnt(6)"  ::: "memory"); }
        else              { asm volatile("s_waitcnt vmcnt(0)"  ::: "memory"); }
        __builtin_amdgcn_sched_barrier(0);
        __builtin_amdgcn_s_barrier();
        __builtin_amdgcn_sched_barrier(0);
        if (t + 5 < 16) stage(t + 5);
        const int slot = t % TBUF;
#pragma unroll
        for (int kk = 0; kk < 64; kk += 32) {
            const int ka = kk + ((lane >> 4) << 3);
            short8 afh[2], afl[2], bh, bl;
#pragma unroll
            for (int m = 0; m < 2; ++m) {
                afh[m] = *reinterpret_cast<const short8*>(&AhS[slot][m * 16 + (lane & 15)][ka]);
                afl[m] = *reinterpret_cast<const short8*>(&AlS[slot][m * 16 + (lane & 15)][ka]);
            }
            bh = *reinterpret_cast<const short8*>(&BhS[slot][wid * 16 + (lane & 15)][ka]);
            bl = *reinterpret_cast<const short8*>(&BlS[slot][wid * 16 + (lane & 15)][ka]);
#pragma unroll
            for (int m = 0; m < 2; ++m) {
                acc[m] = __builtin_amdgcn_mfma_f32_16x16x32_bf16(afh[m], bh, acc[m], 0, 0, 0);
                acc[m] = __builtin_amdgcn_mfma_f32_16x16x32_bf16(afh[m], bl, acc[m], 0, 0, 0);
                acc[m] = __builtin_amdgcn_mfma_f32_16x16x32_bf16(afl[m], bh, acc[m], 0, 0, 0);
            }
        }
    }

    const int dr = (lane >> 4) << 2;
    const int dc = lane & 15;
    const float c13 = 1.0f / 3.0f, c23 = 2.0f / 3.0f;
#pragma unroll
    for (int m = 0; m < 2; ++m) {
        int rbase = m0 + m * 16 + dr;
        if (rbase >= n) continue;
        int col = e0 + wid * 16 + dc;
        float hv[4];
#pragma unroll
        for (int j = 0; j < 4; ++j) {
            int row = rbase + j;
            hv[j] = (row < n) ? tanhf(acc[m][j] + x[(size_t)row * D + col]) : 0.f;
        }
        if (FINAL) {
            if (rbase == 0) out[col] = hv[0];
        } else {
            int p = rbase >> 2;
            float u = hv[0] + c23 * hv[1] + c13 * hv[2];
            float v = c13 * hv[1] + c23 * hv[2] + hv[3];
            unsigned short h_, l_;
            split(u, h_, l_);
            nAh[(size_t)p * KDIM + col] = h_;
            nAl[(size_t)p * KDIM + col] = l_;
            split(v, h_, l_);
            nAh[(size_t)p * KDIM + 512 + col] = h_;
            nAl[(size_t)p * KDIM + 512 + col] = l_;
        }
    }
}

extern "C" void kernel_launch(void* const* d_in, const int* in_sizes, int n_in,
                              void* d_out, int out_size, void* d_ws, size_t ws_size,
                              hipStream_t stream) {
    const float* vectors = (const float*)d_in[0];
    const float* wl = (const float*)d_in[1];
    const float* wr = (const float*)d_in[2];
    float* out = (float*)d_out;
    char* ws = (char*)d_ws;

    size_t cur = 0;
    auto alloc = [&](size_t bytes) -> char* {
        char* p = ws + cur;
        cur += (bytes + 255) & ~(size_t)255;
        return p;
    };
    unsigned short* Wh = (unsigned short*)alloc((size_t)512 * 1024 * 2);
    unsigned short* Wl = (unsigned short*)alloc((size_t)512 * 1024 * 2);
    const int arows[8] = {32, 32, 32, 64, 256, 1024, 4096, 16384};
    unsigned short *Ah[8], *Al[8];
    for (int l = 7; l >= 0; --l) {
        Ah[l] = (unsigned short*)alloc((size_t)arows[l] * KDIM * 2);
        Al[l] = (unsigned short*)alloc((size_t)arows[l] * KDIM * 2);  // Al[7], Al[6] unused
    }
    // levels 2,1,0 allocated last & contiguously: 6 x 64KiB = 384 KiB sliver region

    size_t off8 = 0;
    { size_t o = 0, c = 1; for (int l = 0; l <= 8; ++l) { if (l == 8) off8 = o; o += c; c *= 4; } }
    size_t off7 = off8 - 16384;

    // merged pre-pass: leaf reduce + W split + pad zero
    pre_kernel<<<6240, 256, 0, stream>>>(vectors + off8 * (size_t)D, wl, wr,
                                         Ah[7], Wh, Wl, Ah[2]);

    // level 7: n=16384, BM=128, single product Ah*Wh, writes A6 hi only
    gemm_l7<<<dim3(128, 4), 256, 0, stream>>>(
        Ah[7], Wh, vectors + off7 * (size_t)D, Ah[6], 16384);

    // level 6: n=4096, BM=64xBN=128, single product, 4-deep pipeline, writes A5 hi+lo
    gemm_mid<<<dim3(64, 4), 256, 0, stream>>>(
        Ah[6], Wh, vectors + (off7 - 4096) * (size_t)D, Ah[5], Al[5], 4096);

    // levels 5..0: separate tiny pipelined launches (full bf16x3)
    const int xo[6] = {0, 1, 5, 21, 85, 341};   // (4^l-1)/3
    for (int l = 5; l >= 1; --l) {
        int n = 1 << (2 * l);
        int gx = (n + 31) / 32;
        gemm_tiny<false><<<dim3(gx, 8), 256, 0, stream>>>(
            Ah[l], Al[l], Wh, Wl, vectors + (size_t)xo[l] * D,
            Ah[l - 1], Al[l - 1], nullptr, n);
    }
    gemm_tiny<true><<<dim3(1, 8), 256, 0, stream>>>(
        Ah[0], Al[0], Wh, Wl, vectors, nullptr, nullptr, out, 1);
}